// Round 11
// baseline (62.474 us; speedup 1.0000x reference)
//
#include <hip/hip_runtime.h>

#define BATCH    16
#define NANCH    25200
#define TPB      512
#define NWAVES   (TPB / 64)
#define MAXK     50
#define PRETOPK  2048
#define CONF_T   0.25f
#define IOU_T    0.45f
#define NEGV     -1000000000.0f
#define T0       0.9905f   // fixed collect threshold: E[cnt]=239/batch
#define CAP      320       // total candidate capacity per batch
#define SPLIT    16        // collect slices per batch
#define PERBLK   1575      // NANCH / SPLIT (exact)
#define SCAP     96        // per-slice key capacity (E=15; P(>96) ~ 0)
#define NCOLLECT (BATCH * SPLIT)        // 256 collector blocks
#define GRID     (NCOLLECT + BATCH)     // + 16 NMS blocks
#define SPIN_MAX 200000

// key: [score_bits:32][zeros:16][65535-idx:16]; u64 desc == (score desc, idx asc).
__device__ __forceinline__ unsigned long long make_key(float s, int idx) {
    return ((unsigned long long)__float_as_uint(s) << 32) |
           (unsigned long long)(65535 - idx);
}

// 24-bit order-independent content hash (XOR-fold of position-salted mixes).
__device__ __forceinline__ unsigned int key_contrib(unsigned long long key, int j) {
    unsigned long long t = key ^ (0x9E3779B97F4A7C15ULL * (unsigned long long)(j + 1));
    t *= 0xC2B2AE3D27D4EB4FULL;
    return (unsigned int)(t >> 40);
}
// flag: [count:8][hash:24]. Never 0; poison 0xAAAAAAAA has count=170>SCAP -> invalid.
__device__ __forceinline__ unsigned int flag_word(int idx, int count, unsigned int h24) {
    unsigned int h = 0x5A17F00Du ^ ((unsigned)idx * 0x01000193u)
                   ^ ((unsigned)count * 0x85EBCA6Bu) ^ h24;
    h ^= h >> 12;
    h &= 0xFFFFFFu;
    if (h == 0u) h = 1u;
    return ((unsigned)count << 24) | h;
}

// ---------------------------------------------------------------------------
// Single-dispatch fused kernel. Blocks 0..255: collect one 1575-anchor slice,
// publish {keys, flag} (release). Blocks 256..271: spin-acquire the 16 slice
// flags of their batch (hash-validated; stale data from a previous replay is
// bit-identical so any mix is correct), then rank + tile-greedy (R5-R9
// validated). Invalid/overflow flags -> exact full fallback reading x.
// No grid.sync, no memset, no cross-call state dependence.
// ---------------------------------------------------------------------------
__global__ __launch_bounds__(TPB, 1) void fused_kernel(
        const float* __restrict__ x,
        unsigned long long* __restrict__ skeys,
        unsigned int* __restrict__ scnt,
        float* __restrict__ gscores,
        float* __restrict__ out) {
    __shared__ unsigned long long l_keys[SCAP];
    __shared__ __align__(16) unsigned long long s_keys[CAP];
    __shared__ float s_srows[CAP][8];
    __shared__ float s_kx1[MAXK], s_ky1[MAXK], s_kx2[MAXK], s_ky2[MAXK], s_ka[MAXK];
    __shared__ float s_wval[NWAVES];
    __shared__ int   s_widx[NWAVES];
    __shared__ int   s_slc[SPLIT], s_soff[SPLIT];
    __shared__ int   s_lcnt, s_cnt, s_bad, s_nk, s_best;

    const int bid  = blockIdx.x;
    const int tid  = threadIdx.x;
    const int lane = tid & 63;
    const int wave = tid >> 6;

    // ================= collector blocks =================
    if (bid < NCOLLECT) {
        const int cb   = bid >> 4;
        const int cs   = bid & 15;
        const int base = cs * PERBLK;
        const float* __restrict__ cxb = x + (size_t)cb * NANCH * 6;

        if (tid == 0) s_lcnt = 0;
        __syncthreads();
        #pragma unroll
        for (int k = 0; k < 4; ++k) {          // 4*512 = 2048 >= 1575
            const int i = base + tid + k * TPB;
            if (i < base + PERBLK) {
                const float v = cxb[(size_t)i * 6 + 4];
                if (v > T0) {
                    int slot = atomicAdd(&s_lcnt, 1);   // LDS atomic
                    if (slot < SCAP) l_keys[slot] = make_key(v, i);
                }
            }
        }
        __syncthreads();
        const int  raw = s_lcnt;
        const bool over = raw > SCAP;
        const int  cc  = over ? SCAP : raw;
        for (int j = tid; j < cc; j += TPB)
            skeys[(size_t)bid * SCAP + j] = l_keys[j];
        __threadfence();          // each writer releases its own stores
        __syncthreads();
        if (wave == 0) {
            unsigned int flag;
            if (over) {
                flag = (0xFFu << 24) | 1u;
            } else {
                unsigned int h = 0;
                for (int j = lane; j < cc; j += 64) h ^= key_contrib(l_keys[j], j);
                #pragma unroll
                for (int o = 1; o < 64; o <<= 1) h ^= __shfl_xor(h, o);
                flag = flag_word(bid, cc, h);
            }
            if (lane == 0)
                __hip_atomic_store(&scnt[bid], flag, __ATOMIC_RELEASE,
                                   __HIP_MEMORY_SCOPE_AGENT);
        }
        return;
    }

    // ================= NMS blocks =================
    const int b = bid - NCOLLECT;
    const float* __restrict__ xb = x + (size_t)b * NANCH * 6;
    float* __restrict__ gs       = gscores + (size_t)b * NANCH;
    float* __restrict__ ob       = out + (size_t)b * MAXK * 6;

    if (tid < CAP) s_keys[tid] = 0ULL;
    if (tid == 0) s_nk = 0;

    // ---- handshake: wave w validates slices w and w+8 ----
    for (int s = wave; s < SPLIT; s += NWAVES) {
        const int idx = b * SPLIT + s;
        int got = -1;
        for (int t = 0; t < SPIN_MAX; ++t) {
            unsigned int f = 0;
            if (lane == 0)
                f = __hip_atomic_load(&scnt[idx], __ATOMIC_ACQUIRE,
                                      __HIP_MEMORY_SCOPE_AGENT);
            f = __shfl(f, 0);                       // uniform view
            const unsigned int c = f >> 24;
            if (c == 0xFFu) { got = -2; break; }    // overflow -> exact fallback
            if (c <= SCAP) {
                __threadfence();                    // acquire side
                unsigned int h = 0;
                for (int j = lane; j < (int)c; j += 64)
                    h ^= key_contrib(skeys[(size_t)idx * SCAP + j], j);
                #pragma unroll
                for (int o = 1; o < 64; o <<= 1) h ^= __shfl_xor(h, o);
                if (flag_word(idx, (int)c, h) == f) { got = (int)c; break; }
            }
            __builtin_amdgcn_s_sleep(8);
        }
        if (lane == 0) s_slc[s] = (got < 0) ? -1 : got;
    }
    __syncthreads();

    if (tid == 0) {
        int off = 0, bad = 0;
        #pragma unroll
        for (int s = 0; s < SPLIT; ++s) {
            s_soff[s] = off;
            const int c = s_slc[s];
            bad |= (c < 0);
            off += (c < 0) ? 0 : c;
        }
        s_cnt = off;
        s_bad = bad | (off > CAP);
    }
    __syncthreads();

    const bool fast = !s_bad;
    const int  cnt  = fast ? s_cnt : 0;

    if (fast) {
        // gather keys compactly: 32 threads per slice
        {
            const int s = tid >> 5, j0 = tid & 31;
            const int c = s_slc[s], o = s_soff[s];
            for (int j = j0; j < c; j += 32)
                s_keys[o + j] = skeys[(size_t)(b * SPLIT + s) * SCAP + j];
        }
        __syncthreads();

        // ---- counting-rank + rank-ordered row gather (threads 0..319) ----
        if (tid < CAP) {
            const unsigned long long mykey = s_keys[tid];
            float2 r0, r1, r2;
            const bool real = tid < cnt;
            if (real) {   // issue row fetch early; hides under rank loop
                int myi = 65535 - (int)(mykey & 0xFFFFULL);
                const float2* rp = (const float2*)(xb + (size_t)myi * 6);
                r0 = rp[0]; r1 = rp[1]; r2 = rp[2];
            }
            int r = 0;
            const ulonglong2* kp = (const ulonglong2*)s_keys;
            #pragma unroll 4
            for (int j = 0; j < CAP / 2; ++j) {
                const ulonglong2 p = kp[j];
                r += (p.x > mykey) ? 1 : 0;
                r += (p.y > mykey) ? 1 : 0;
            }
            if (real) {
                s_srows[r][0] = r0.x; s_srows[r][1] = r0.y;
                s_srows[r][2] = r1.x; s_srows[r][3] = r1.y;
                s_srows[r][4] = r2.x; s_srows[r][5] = r2.y;
            }
        }
        __syncthreads();

        // ---- wave 0: 64-wide tile greedy over sorted rows ----
        if (wave == 0) {
            int nk = 0;
            for (int tb = 0; tb < cnt && nk < MAXK; tb += 64) {
                const int lim = (cnt - tb) < 64 ? (cnt - tb) : 64;
                float4 bx = {0.f, 0.f, 0.f, 0.f};
                float2 be = {0.f, 0.f};
                bool sup = lane >= lim;
                if (!sup) {
                    bx = *(const float4*)&s_srows[tb + lane][0];
                    be = *(const float2*)&s_srows[tb + lane][4];
                }
                const float ba = fmaxf(bx.z - bx.x, 0.f) * fmaxf(bx.w - bx.y, 0.f);

                for (int j = 0; j < nk; ++j) {
                    float iw = fmaxf(fminf(bx.z, s_kx2[j]) - fmaxf(bx.x, s_kx1[j]), 0.f);
                    float ih = fmaxf(fminf(bx.w, s_ky2[j]) - fmaxf(bx.y, s_ky1[j]), 0.f);
                    float inter = iw * ih;
                    sup = sup || (inter / fmaxf(ba + s_ka[j] - inter, 1e-9f)) >= IOU_T;
                }

                unsigned long long m = 0ULL;
                #pragma unroll 8
                for (int j = 0; j < 64; ++j) {
                    if (j >= lim) break;
                    const float4 oj = *(const float4*)&s_srows[tb + j][0];
                    const float oa = fmaxf(oj.z - oj.x, 0.f) * fmaxf(oj.w - oj.y, 0.f);
                    float iw = fmaxf(fminf(bx.z, oj.z) - fmaxf(bx.x, oj.x), 0.f);
                    float ih = fmaxf(fminf(bx.w, oj.w) - fmaxf(bx.y, oj.y), 0.f);
                    float inter = iw * ih;
                    bool ov = (inter / fmaxf(ba + oa - inter, 1e-9f)) >= IOU_T;
                    m |= ov ? (1ULL << j) : 0ULL;
                }
                m &= ~(1ULL << lane);

                unsigned long long alive = __ballot(!sup);
                unsigned long long keepmask = 0ULL;
                while (alive != 0ULL && nk < MAXK) {
                    const int j = __builtin_ctzll(alive);
                    keepmask |= 1ULL << j;
                    ++nk;
                    const unsigned long long kill = __ballot((m >> j) & 1ULL);
                    alive &= ~(kill | (1ULL << j));
                }

                if ((keepmask >> lane) & 1ULL) {
                    const int nk0 = nk - __popcll(keepmask);
                    const int pos = nk0 + __popcll(keepmask & ((1ULL << lane) - 1ULL));
                    s_kx1[pos] = bx.x; s_ky1[pos] = bx.y;
                    s_kx2[pos] = bx.z; s_ky2[pos] = bx.w; s_ka[pos] = ba;
                    ob[pos * 6 + 0] = bx.x;
                    ob[pos * 6 + 1] = bx.y;
                    ob[pos * 6 + 2] = bx.z;
                    ob[pos * 6 + 3] = bx.w;
                    ob[pos * 6 + 4] = be.x;
                    ob[pos * 6 + 5] = be.y;
                }
            }
            if (lane == 0) s_nk = nk;
        }
        __syncthreads();
    }

    // ---- fallback / continuation (exact; never taken on this data) ----
    // Build a private score array in ws (fully rewritten before use -> no
    // cross-call state), then iterative argmax with the remaining budget.
    if (!fast || s_nk < MAXK) {
        for (int i = tid; i < NANCH; i += TPB) {
            const float sc = xb[(size_t)i * 6 + 4];
            const bool dead = (sc <= CONF_T) || (fast && sc > T0);
            gs[i] = dead ? NEGV : sc;
        }
        __syncthreads();

        const int budget = fast ? (PRETOPK - cnt) : PRETOPK;
        int nk = s_nk;
        for (int pop = 0; pop < budget && nk < MAXK; ++pop) {
            float bv = NEGV - 1.0f;
            int   bi = NANCH;
            for (int i = tid; i < NANCH; i += TPB) {
                const float v = gs[i];
                if (v > bv) { bv = v; bi = i; }
            }
            #pragma unroll
            for (int off = 32; off >= 1; off >>= 1) {
                float ov = __shfl_down(bv, off);
                int   oi = __shfl_down(bi, off);
                if (ov > bv || (ov == bv && oi < bi)) { bv = ov; bi = oi; }
            }
            if (lane == 0) { s_wval[wave] = bv; s_widx[wave] = bi; }
            __syncthreads();
            if (wave == 0) {
                bv = (lane < NWAVES) ? s_wval[lane] : (NEGV - 1.0f);
                bi = (lane < NWAVES) ? s_widx[lane] : NANCH;
                #pragma unroll
                for (int off = 32; off >= 1; off >>= 1) {
                    float ov = __shfl_down(bv, off);
                    int   oi = __shfl_down(bi, off);
                    if (ov > bv || (ov == bv && oi < bi)) { bv = ov; bi = oi; }
                }
                if (lane == 0) {
                    s_best = (bv > 0.5f * NEGV) ? bi : -1;
                    if (s_best >= 0) gs[bi] = NEGV;   // pop
                }
            }
            __syncthreads();
            const int best = s_best;
            if (best < 0) break;

            if (wave == 0) {
                const float bx1 = xb[(size_t)best * 6 + 0];
                const float by1 = xb[(size_t)best * 6 + 1];
                const float bx2 = xb[(size_t)best * 6 + 2];
                const float by2 = xb[(size_t)best * 6 + 3];
                const float ba  = fmaxf(bx2 - bx1, 0.0f) * fmaxf(by2 - by1, 0.0f);
                bool sup = false;
                if (lane < nk) {
                    float iw = fmaxf(fminf(bx2, s_kx2[lane]) - fmaxf(bx1, s_kx1[lane]), 0.f);
                    float ih = fmaxf(fminf(by2, s_ky2[lane]) - fmaxf(by1, s_ky1[lane]), 0.f);
                    float inter = iw * ih;
                    float uni   = ba + s_ka[lane] - inter;
                    sup = (inter / fmaxf(uni, 1e-9f)) >= IOU_T;
                }
                if (lane == 0 && __ballot(sup) == 0ULL) {
                    s_kx1[nk] = bx1; s_ky1[nk] = by1;
                    s_kx2[nk] = bx2; s_ky2[nk] = by2; s_ka[nk] = ba;
                    ob[nk * 6 + 0] = bx1;
                    ob[nk * 6 + 1] = by1;
                    ob[nk * 6 + 2] = bx2;
                    ob[nk * 6 + 3] = by2;
                    ob[nk * 6 + 4] = xb[(size_t)best * 6 + 4];
                    ob[nk * 6 + 5] = xb[(size_t)best * 6 + 5];
                    s_nk = nk + 1;
                }
            }
            __syncthreads();
            nk = s_nk;
        }
        __syncthreads();
    }

    const int nkf = s_nk;
    for (int i = tid; i < (MAXK - nkf) * 6; i += TPB) {
        ob[nkf * 6 + i] = -1.0f;
    }
}

// ---------------------------------------------------------------------------
// No-workspace fallback: R1-validated self-contained iterative-argmax NMS.
// ---------------------------------------------------------------------------
__global__ __launch_bounds__(TPB, 1) void legacy_kernel(const float* __restrict__ x,
                                                        float* __restrict__ out) {
    __shared__ float s_scores[NANCH];
    __shared__ float s_kx1[MAXK], s_ky1[MAXK], s_kx2[MAXK], s_ky2[MAXK], s_ka[MAXK];
    __shared__ float s_wval[NWAVES];
    __shared__ int   s_widx[NWAVES];
    __shared__ int   s_nk, s_best;

    const int b    = blockIdx.x;
    const int tid  = threadIdx.x;
    const int lane = tid & 63;
    const int wave = tid >> 6;

    const float* __restrict__ xb = x + (size_t)b * NANCH * 6;
    float* __restrict__ ob       = out + (size_t)b * MAXK * 6;

    for (int i = tid; i < NANCH; i += TPB) {
        const float s = xb[(size_t)i * 6 + 4];
        s_scores[i] = (s > CONF_T) ? s : NEGV;
    }
    if (tid == 0) s_nk = 0;
    __syncthreads();

    int nk = 0;
    for (int pop = 0; pop < PRETOPK && nk < MAXK; ++pop) {
        float bv = NEGV - 1.0f;
        int   bi = NANCH;
        for (int i = tid; i < NANCH; i += TPB) {
            const float s = s_scores[i];
            if (s > bv) { bv = s; bi = i; }
        }
        #pragma unroll
        for (int off = 32; off >= 1; off >>= 1) {
            float ov = __shfl_down(bv, off);
            int   oi = __shfl_down(bi, off);
            if (ov > bv || (ov == bv && oi < bi)) { bv = ov; bi = oi; }
        }
        if (lane == 0) { s_wval[wave] = bv; s_widx[wave] = bi; }
        __syncthreads();
        if (wave == 0) {
            bv = (lane < NWAVES) ? s_wval[lane] : (NEGV - 1.0f);
            bi = (lane < NWAVES) ? s_widx[lane] : NANCH;
            #pragma unroll
            for (int off = 32; off >= 1; off >>= 1) {
                float ov = __shfl_down(bv, off);
                int   oi = __shfl_down(bi, off);
                if (ov > bv || (ov == bv && oi < bi)) { bv = ov; bi = oi; }
            }
            if (lane == 0) {
                s_best = (bv > 0.5f * NEGV) ? bi : -1;
                if (s_best >= 0) s_scores[bi] = NEGV - 1.0f;
            }
        }
        __syncthreads();
        const int best = s_best;
        if (best < 0) break;

        if (wave == 0) {
            const float bx1 = xb[(size_t)best * 6 + 0];
            const float by1 = xb[(size_t)best * 6 + 1];
            const float bx2 = xb[(size_t)best * 6 + 2];
            const float by2 = xb[(size_t)best * 6 + 3];
            const float ba  = fmaxf(bx2 - bx1, 0.0f) * fmaxf(by2 - by1, 0.0f);
            bool sup = false;
            if (lane < nk) {
                float iw = fmaxf(fminf(bx2, s_kx2[lane]) - fmaxf(bx1, s_kx1[lane]), 0.f);
                float ih = fmaxf(fminf(by2, s_ky2[lane]) - fmaxf(by1, s_ky1[lane]), 0.f);
                float inter = iw * ih;
                float uni   = ba + s_ka[lane] - inter;
                sup = (inter / fmaxf(uni, 1e-9f)) >= IOU_T;
            }
            if (lane == 0 && __ballot(sup) == 0ULL) {
                s_kx1[nk] = bx1; s_ky1[nk] = by1;
                s_kx2[nk] = bx2; s_ky2[nk] = by2; s_ka[nk] = ba;
                ob[nk * 6 + 0] = bx1;
                ob[nk * 6 + 1] = by1;
                ob[nk * 6 + 2] = bx2;
                ob[nk * 6 + 3] = by2;
                ob[nk * 6 + 4] = xb[(size_t)best * 6 + 4];
                ob[nk * 6 + 5] = xb[(size_t)best * 6 + 5];
                s_nk = nk + 1;
            }
        }
        __syncthreads();
        nk = s_nk;
    }
    __syncthreads();

    const int nkf = s_nk;
    for (int i = tid; i < (MAXK - nkf) * 6; i += TPB) {
        ob[nkf * 6 + i] = -1.0f;
    }
}

extern "C" void kernel_launch(void* const* d_in, const int* in_sizes, int n_in,
                              void* d_out, int out_size, void* d_ws, size_t ws_size,
                              hipStream_t stream) {
    const float* x = (const float*)d_in[0];
    float* out     = (float*)d_out;

    const size_t key_off = 4096;                                           // flags pad
    const size_t key_sz  = (size_t)NCOLLECT * SCAP * sizeof(unsigned long long);
    const size_t gs_off  = key_off + key_sz;
    const size_t gs_sz   = (size_t)BATCH * NANCH * sizeof(float);
    if (d_ws != nullptr && ws_size >= gs_off + gs_sz) {
        unsigned int* scnt        = (unsigned int*)d_ws;
        unsigned long long* skeys = (unsigned long long*)((char*)d_ws + key_off);
        float* gscores            = (float*)((char*)d_ws + gs_off);
        fused_kernel<<<GRID, TPB, 0, stream>>>(x, skeys, scnt, gscores, out);
    } else {
        legacy_kernel<<<BATCH, TPB, 0, stream>>>(x, out);
    }
}

// Round 12
// 25.716 us; speedup vs baseline: 2.4294x; 2.4294x over previous
//
#include <hip/hip_runtime.h>

#define BATCH   16
#define NANCH   25200
#define TPB     512
#define NWAVES  (TPB / 64)
#define MAXK    50
#define PRETOPK 2048
#define CONF_T  0.25f
#define IOU_T   0.45f
#define NEGV    -1000000000.0f
#define T0      0.9905f   // fixed collect threshold: E[cnt]=239/batch
#define CAP     320       // total candidate capacity per batch
#define SPLIT   32        // K1 slices per batch
#define K1B     256
#define PERBLK  788       // ceil(NANCH/SPLIT); last slice bounded by NANCH
#define SCAP    96        // per-slice key capacity (E=7.5; P(>96) ~ 0)

// key: [score_bits:32][zeros:16][65535-idx:16]; u64 desc == (score desc, idx asc).
__device__ __forceinline__ unsigned long long make_key(float s, int idx) {
    return ((unsigned long long)__float_as_uint(s) << 32) |
           (unsigned long long)(65535 - idx);
}

// K1: full-machine candidate collection (512 blocks, 2/CU). LDS-local count,
// private ws region per block fully rewritten every call -> replay-safe.
__global__ __launch_bounds__(K1B) void collect_kernel(const float* __restrict__ x,
                                                      unsigned long long* __restrict__ skeys,
                                                      unsigned int* __restrict__ scnt) {
    __shared__ unsigned long long l_keys[SCAP];
    __shared__ int l_cnt;
    const int b    = blockIdx.x >> 5;
    const int s    = blockIdx.x & 31;
    const int base = s * PERBLK;
    const int end  = (base + PERBLK < NANCH) ? base + PERBLK : NANCH;
    const float* __restrict__ xb = x + (size_t)b * NANCH * 6;

    if (threadIdx.x == 0) l_cnt = 0;
    __syncthreads();

    #pragma unroll
    for (int k = 0; k < 4; ++k) {          // 4*256 = 1024 >= 788
        const int i = base + (int)threadIdx.x + k * K1B;
        if (i < end) {
            const float v = xb[(size_t)i * 6 + 4];
            if (v > T0) {
                int slot = atomicAdd(&l_cnt, 1);       // LDS atomic
                if (slot < SCAP) l_keys[slot] = make_key(v, i);
            }
        }
    }
    __syncthreads();

    const int c = l_cnt;
    if (threadIdx.x == 0) scnt[blockIdx.x] = (unsigned)c;
    const int cc = c < SCAP ? c : SCAP;
    for (int j = (int)threadIdx.x; j < cc; j += K1B)
        skeys[(size_t)blockIdx.x * SCAP + j] = l_keys[j];
}

// K2: one workgroup per batch, 8 waves. Fast path: gather ~240 keys ->
// counting-rank (exact lax.top_k tie order, b128 LDS reads) + row gather ->
// 64-wide tile greedy (R5-R9 validated). Fallback (exact, never taken on
// this data): stage scores from global, iterative argmax, 2048-pop budget.
__global__ __launch_bounds__(TPB, 1) void nms_kernel(const float* __restrict__ x,
                                                     const unsigned long long* __restrict__ skeys,
                                                     const unsigned int* __restrict__ scnt,
                                                     float* __restrict__ out) {
    __shared__ float s_scores[NANCH];                      // fallback only
    __shared__ __align__(16) unsigned long long s_keys[CAP];
    __shared__ float s_srows[CAP][8];
    __shared__ float s_kx1[MAXK], s_ky1[MAXK], s_kx2[MAXK], s_ky2[MAXK], s_ka[MAXK];
    __shared__ float s_wval[NWAVES];
    __shared__ int   s_widx[NWAVES];
    __shared__ int   s_slc[SPLIT], s_soff[SPLIT];
    __shared__ int   s_cnt, s_bad, s_nk, s_best;

    const int b    = blockIdx.x;
    const int tid  = threadIdx.x;
    const int lane = tid & 63;
    const int wave = tid >> 6;

    const float* __restrict__ xb = x + (size_t)b * NANCH * 6;
    float* __restrict__ ob       = out + (size_t)b * MAXK * 6;

    if (tid < CAP) s_keys[tid] = 0ULL;
    if (tid < SPLIT) s_slc[tid] = scnt ? (int)scnt[b * SPLIT + tid] : SCAP + 1;
    if (tid == 0) s_nk = 0;
    __syncthreads();
    if (tid == 0) {
        int off = 0, bad = 0;
        #pragma unroll
        for (int s = 0; s < SPLIT; ++s) {
            s_soff[s] = off;
            off += s_slc[s];
            bad |= (s_slc[s] > SCAP);
        }
        s_cnt = off;
        s_bad = bad | (off > CAP);
    }
    __syncthreads();

    const bool fast = !s_bad;
    const int  cnt  = fast ? s_cnt : 0;

    if (fast) {
        // gather keys compactly: 16 threads per slice (32 slices x 16 = 512)
        {
            const int s = tid >> 4, j0 = tid & 15;
            const int c = s_slc[s], o = s_soff[s];
            for (int j = j0; j < c; j += 16)
                s_keys[o + j] = skeys[(size_t)(b * SPLIT + s) * SCAP + j];
        }
        __syncthreads();

        // ---- counting-rank + rank-ordered row gather (threads 0..319) ----
        if (tid < CAP) {
            const unsigned long long mykey = s_keys[tid];
            float2 r0, r1, r2;
            const bool real = tid < cnt;
            if (real) {   // issue row fetch early; hides under rank loop
                int myi = 65535 - (int)(mykey & 0xFFFFULL);
                const float2* rp = (const float2*)(xb + (size_t)myi * 6);
                r0 = rp[0]; r1 = rp[1]; r2 = rp[2];
            }
            int r = 0;
            const ulonglong2* kp = (const ulonglong2*)s_keys;
            #pragma unroll 4
            for (int j = 0; j < CAP / 2; ++j) {
                const ulonglong2 p = kp[j];
                r += (p.x > mykey) ? 1 : 0;
                r += (p.y > mykey) ? 1 : 0;
            }
            if (real) {
                s_srows[r][0] = r0.x; s_srows[r][1] = r0.y;
                s_srows[r][2] = r1.x; s_srows[r][3] = r1.y;
                s_srows[r][4] = r2.x; s_srows[r][5] = r2.y;
            }
        }
        __syncthreads();

        // ---- wave 0: 64-wide tile greedy over sorted rows ----
        if (wave == 0) {
            int nk = 0;
            for (int tb = 0; tb < cnt && nk < MAXK; tb += 64) {
                const int lim = (cnt - tb) < 64 ? (cnt - tb) : 64;
                float4 bx = {0.f, 0.f, 0.f, 0.f};
                float2 be = {0.f, 0.f};
                bool sup = lane >= lim;
                if (!sup) {
                    bx = *(const float4*)&s_srows[tb + lane][0];
                    be = *(const float2*)&s_srows[tb + lane][4];
                }
                const float ba = fmaxf(bx.z - bx.x, 0.f) * fmaxf(bx.w - bx.y, 0.f);

                // (A) vs previously-kept boxes (empty on 1st tile)
                for (int j = 0; j < nk; ++j) {
                    float iw = fmaxf(fminf(bx.z, s_kx2[j]) - fmaxf(bx.x, s_kx1[j]), 0.f);
                    float ih = fmaxf(fminf(bx.w, s_ky2[j]) - fmaxf(bx.y, s_ky1[j]), 0.f);
                    float inter = iw * ih;
                    sup = sup || (inter / fmaxf(ba + s_ka[j] - inter, 1e-9f)) >= IOU_T;
                }

                // (B) pairwise overlap mask within tile (symmetric; pure VALU)
                unsigned long long m = 0ULL;
                #pragma unroll 8
                for (int j = 0; j < 64; ++j) {
                    if (j >= lim) break;
                    const float4 oj = *(const float4*)&s_srows[tb + j][0];
                    const float oa = fmaxf(oj.z - oj.x, 0.f) * fmaxf(oj.w - oj.y, 0.f);
                    float iw = fmaxf(fminf(bx.z, oj.z) - fmaxf(bx.x, oj.x), 0.f);
                    float ih = fmaxf(fminf(bx.w, oj.w) - fmaxf(bx.y, oj.y), 0.f);
                    float inter = iw * ih;
                    bool ov = (inter / fmaxf(ba + oa - inter, 1e-9f)) >= IOU_T;
                    m |= ov ? (1ULL << j) : 0ULL;
                }
                m &= ~(1ULL << lane);

                // (C) sequential resolve with cheap ops only
                unsigned long long alive = __ballot(!sup);
                unsigned long long keepmask = 0ULL;
                while (alive != 0ULL && nk < MAXK) {
                    const int j = __builtin_ctzll(alive);
                    keepmask |= 1ULL << j;
                    ++nk;
                    const unsigned long long kill = __ballot((m >> j) & 1ULL);
                    alive &= ~(kill | (1ULL << j));
                }

                // (D) parallel write of kept rows (exact greedy order)
                if ((keepmask >> lane) & 1ULL) {
                    const int nk0 = nk - __popcll(keepmask);
                    const int pos = nk0 + __popcll(keepmask & ((1ULL << lane) - 1ULL));
                    s_kx1[pos] = bx.x; s_ky1[pos] = bx.y;
                    s_kx2[pos] = bx.z; s_ky2[pos] = bx.w; s_ka[pos] = ba;
                    ob[pos * 6 + 0] = bx.x;
                    ob[pos * 6 + 1] = bx.y;
                    ob[pos * 6 + 2] = bx.z;
                    ob[pos * 6 + 3] = bx.w;
                    ob[pos * 6 + 4] = be.x;
                    ob[pos * 6 + 5] = be.y;
                }
            }
            if (lane == 0) s_nk = nk;
        }
        __syncthreads();
    }

    // ---- fallback / continuation (exact; never taken on this data) ----
    const bool need_fb = !fast || (s_nk < MAXK);
    if (need_fb) {
        for (int i = tid; i < NANCH; i += TPB) {
            float sc = xb[(size_t)i * 6 + 4];
            bool dead = (sc <= CONF_T) || (fast && sc > T0);
            s_scores[i] = dead ? NEGV : sc;
        }
        __syncthreads();

        const int budget = fast ? (PRETOPK - cnt) : PRETOPK;
        int nk = s_nk;
        for (int pop = 0; pop < budget && nk < MAXK; ++pop) {
            float bv = NEGV - 1.0f;
            int   bi = NANCH;
            for (int i = tid; i < NANCH; i += TPB) {
                float sc = s_scores[i];
                if (sc > bv) { bv = sc; bi = i; }
            }
            #pragma unroll
            for (int off = 32; off >= 1; off >>= 1) {
                float ov = __shfl_down(bv, off);
                int   oi = __shfl_down(bi, off);
                if (ov > bv || (ov == bv && oi < bi)) { bv = ov; bi = oi; }
            }
            if (lane == 0) { s_wval[wave] = bv; s_widx[wave] = bi; }
            __syncthreads();
            if (wave == 0) {
                bv = (lane < NWAVES) ? s_wval[lane] : (NEGV - 1.0f);
                bi = (lane < NWAVES) ? s_widx[lane] : NANCH;
                #pragma unroll
                for (int off = 32; off >= 1; off >>= 1) {
                    float ov = __shfl_down(bv, off);
                    int   oi = __shfl_down(bi, off);
                    if (ov > bv || (ov == bv && oi < bi)) { bv = ov; bi = oi; }
                }
                if (lane == 0) {
                    s_best = (bv > 0.5f * NEGV) ? bi : -1;
                    if (s_best >= 0) s_scores[bi] = NEGV - 1.0f;
                }
            }
            __syncthreads();
            const int best = s_best;
            if (best < 0) break;

            if (wave == 0) {
                const float bx1 = xb[(size_t)best * 6 + 0];
                const float by1 = xb[(size_t)best * 6 + 1];
                const float bx2 = xb[(size_t)best * 6 + 2];
                const float by2 = xb[(size_t)best * 6 + 3];
                const float ba  = fmaxf(bx2 - bx1, 0.0f) * fmaxf(by2 - by1, 0.0f);
                bool sup = false;
                if (lane < nk) {
                    float iw = fmaxf(fminf(bx2, s_kx2[lane]) - fmaxf(bx1, s_kx1[lane]), 0.f);
                    float ih = fmaxf(fminf(by2, s_ky2[lane]) - fmaxf(by1, s_ky1[lane]), 0.f);
                    float inter = iw * ih;
                    float uni   = ba + s_ka[lane] - inter;
                    sup = (inter / fmaxf(uni, 1e-9f)) >= IOU_T;
                }
                if (lane == 0 && __ballot(sup) == 0ULL) {
                    s_kx1[nk] = bx1; s_ky1[nk] = by1;
                    s_kx2[nk] = bx2; s_ky2[nk] = by2; s_ka[nk] = ba;
                    ob[nk * 6 + 0] = bx1;
                    ob[nk * 6 + 1] = by1;
                    ob[nk * 6 + 2] = bx2;
                    ob[nk * 6 + 3] = by2;
                    ob[nk * 6 + 4] = xb[(size_t)best * 6 + 4];
                    ob[nk * 6 + 5] = xb[(size_t)best * 6 + 5];
                    s_nk = nk + 1;
                }
            }
            __syncthreads();
            nk = s_nk;
        }
        __syncthreads();
    }

    // Fill remaining rows with -1.0.
    const int nkf = s_nk;
    for (int i = tid; i < (MAXK - nkf) * 6; i += TPB) {
        ob[nkf * 6 + i] = -1.0f;
    }
}

extern "C" void kernel_launch(void* const* d_in, const int* in_sizes, int n_in,
                              void* d_out, int out_size, void* d_ws, size_t ws_size,
                              hipStream_t stream) {
    const float* x = (const float*)d_in[0];
    float* out     = (float*)d_out;

    const size_t key_off   = 4096;  // scnt: 512 u32 = 2KB, padded
    const size_t key_bytes = (size_t)BATCH * SPLIT * SCAP * sizeof(unsigned long long);
    if (d_ws != nullptr && ws_size >= key_off + key_bytes) {
        unsigned int* scnt        = (unsigned int*)d_ws;
        unsigned long long* skeys = (unsigned long long*)((char*)d_ws + key_off);
        collect_kernel<<<BATCH * SPLIT, K1B, 0, stream>>>(x, skeys, scnt);
        nms_kernel<<<BATCH, TPB, 0, stream>>>(x, skeys, scnt, out);
    } else {
        // No workspace: exact fallback path inside nms_kernel.
        nms_kernel<<<BATCH, TPB, 0, stream>>>(x, nullptr, nullptr, out);
    }
}